// Round 3
// baseline (357.711 us; speedup 1.0000x reference)
//
#include <hip/hip_runtime.h>
#include <stdint.h>

// ---------------------------------------------------------------------------
// SelfAttention: LN -> QKV (bf16 MFMA GEMM) -> S=QK^T/32 -> softmax -> att*V
// B=4, N=2048, D=H=1024. Outputs: att fp32 [4,2048,2048] ++ out fp32 [4,2048,1024]
// Scratch plan (OOB-hardened):
//   d_out att region (64 MB, dead until k_scores): xn (16.8 MB) + wt (6.3 MB)
//   d_ws (exactly 50.3 MB): q|k|v, then vt overlays q, attb overlays k+v
// ---------------------------------------------------------------------------

typedef __attribute__((ext_vector_type(8))) short short8;   // 8 bf16 (4 VGPRs)
typedef __attribute__((ext_vector_type(4))) float floatx4;  // MFMA acc
typedef __attribute__((ext_vector_type(4))) uint16_t u16x4;

__device__ __forceinline__ uint16_t f2bf(float f) {
    union { float f; uint32_t u; } v; v.f = f;
    uint32_t r = v.u + 0x7fffu + ((v.u >> 16) & 1u);  // RNE
    return (uint16_t)(r >> 16);
}

// async global->LDS, 16B per lane. LDS dest must be wave-uniform base + lane*16.
typedef const uint32_t __attribute__((address_space(1)))* gas1_t;
typedef uint32_t __attribute__((address_space(3)))* las3_t;
__device__ __forceinline__ void gload_lds16(const uint16_t* g, uint16_t* l) {
    __builtin_amdgcn_global_load_lds((gas1_t)g, (las3_t)l, 16, 0, 0);
}

// ---------------------------------------------------------------------------
// Generic C = A * Bt^T GEMM. A:[M,K] bf16 row-major, Bt:[N,K] bf16 row-major.
// Block tile 128x128, BK=32, 256 threads (4 waves, 2x2 of 64x64 per wave).
// EPI: 0 = fp32 store * alpha;  1 = bf16 store + bias;  2 = fp32 store.
// ---------------------------------------------------------------------------
#define BM 128
#define BN 128
#define BKK 32

template<int EPI>
__device__ __forceinline__ void gemm_bt_body(
    const uint16_t* __restrict__ A, const uint16_t* __restrict__ Bt, int K,
    float* __restrict__ Cf, uint16_t* __restrict__ Cb, int ldc,
    const float* __restrict__ bias, float alpha)
{
    __shared__ uint16_t lA[BM * BKK];  // [128][32] row-major, no padding (global_load_lds)
    __shared__ uint16_t lB[BN * BKK];

    const int t  = threadIdx.x;
    const int m0 = blockIdx.y * BM;
    const int n0 = blockIdx.x * BN;

    // staging: thread t loads 16B at row t/4, colseg (t&3)*8; second chunk +64 rows
    const uint16_t* ga = A + (size_t)(m0 + (t >> 2)) * K + (t & 3) * 8;
    const uint16_t* gb = Bt + (size_t)(n0 + (t >> 2)) * K + (t & 3) * 8;
    uint16_t* la = &lA[t * 8];
    uint16_t* lb = &lB[t * 8];
    const size_t step64 = (size_t)64 * K;

    const int lane = t & 63;
    const int w    = t >> 6;
    const int quad = lane >> 4;
    const int lrow = lane & 15;
    const int wm   = (w & 1) * 64;
    const int wn   = (w >> 1) * 64;

    floatx4 acc[4][4];
#pragma unroll
    for (int i = 0; i < 4; i++)
#pragma unroll
        for (int j = 0; j < 4; j++)
            acc[i][j] = floatx4{0.f, 0.f, 0.f, 0.f};

    for (int k0 = 0; k0 < K; k0 += BKK) {
        __syncthreads();  // LDS reuse guard
        gload_lds16(ga + k0, la);
        gload_lds16(ga + step64 + k0, la + 2048);
        gload_lds16(gb + k0, lb);
        gload_lds16(gb + step64 + k0, lb + 2048);
        __syncthreads();  // drains vmcnt (global_load_lds) + lgkmcnt

        short8 af[4], bf[4];
#pragma unroll
        for (int mi = 0; mi < 4; mi++)
            af[mi] = *(const short8*)&lA[(wm + mi * 16 + lrow) * BKK + quad * 8];
#pragma unroll
        for (int ni = 0; ni < 4; ni++)
            bf[ni] = *(const short8*)&lB[(wn + ni * 16 + lrow) * BKK + quad * 8];
#pragma unroll
        for (int mi = 0; mi < 4; mi++)
#pragma unroll
            for (int ni = 0; ni < 4; ni++)
                acc[mi][ni] = __builtin_amdgcn_mfma_f32_16x16x32_bf16(
                    af[mi], bf[ni], acc[mi][ni], 0, 0, 0);
    }

    // epilogue: C/D layout col=lane&15, row=quad*4+reg  [verified m89/m91]
#pragma unroll
    for (int mi = 0; mi < 4; mi++) {
#pragma unroll
        for (int ni = 0; ni < 4; ni++) {
            const int row = m0 + wm + mi * 16 + quad * 4;
            const int col = n0 + wn + ni * 16 + lrow;
#pragma unroll
            for (int r = 0; r < 4; r++) {
                const float v = acc[mi][ni][r];
                if (EPI == 0) {
                    Cf[(size_t)(row + r) * ldc + col] = v * alpha;
                } else if (EPI == 1) {
                    Cb[(size_t)(row + r) * ldc + col] = f2bf(v + bias[col]);
                } else {
                    Cf[(size_t)(row + r) * ldc + col] = v;
                }
            }
        }
    }
}

// q/k/v = xn @ w{q,k,v} + b   (z selects weight); writes bf16 row-major
__global__ __launch_bounds__(256) void k_qkv(
    const uint16_t* __restrict__ xn, const uint16_t* __restrict__ wt,
    const float* __restrict__ bq, const float* __restrict__ bk,
    const float* __restrict__ bv, uint16_t* __restrict__ qkv)
{
    const int z = blockIdx.z;
    const uint16_t* Bt = wt + (size_t)z * 1024 * 1024;
    const float* bias = (z == 0) ? bq : ((z == 1) ? bk : bv);
    uint16_t* C = qkv + (size_t)z * 8192 * 1024;
    gemm_bt_body<1>(xn, Bt, 1024, nullptr, C, 1024, bias, 0.f);
}

// S = q @ k^T * (1/32), fp32 into d_out att region
__global__ __launch_bounds__(256) void k_scores(
    const uint16_t* __restrict__ q, const uint16_t* __restrict__ k,
    float* __restrict__ S)
{
    const int z = blockIdx.z;
    gemm_bt_body<0>(q + (size_t)z * 2048 * 1024, k + (size_t)z * 2048 * 1024, 1024,
                    S + (size_t)z * 2048 * 2048, nullptr, 2048, nullptr, 0.03125f);
}

// out = att_bf16 @ vt^T, fp32
__global__ __launch_bounds__(256) void k_out(
    const uint16_t* __restrict__ attb, const uint16_t* __restrict__ vt,
    float* __restrict__ out)
{
    const int z = blockIdx.z;
    gemm_bt_body<2>(attb + (size_t)z * 2048 * 2048, vt + (size_t)z * 1024 * 2048, 2048,
                    out + (size_t)z * 2048 * 1024, nullptr, 1024, nullptr, 0.f);
}

// ---------------------------------------------------------------------------
// LayerNorm rows of x[8192][1024] -> bf16 xn
// ---------------------------------------------------------------------------
__global__ __launch_bounds__(256) void k_ln(
    const float* __restrict__ x, const float* __restrict__ lw,
    const float* __restrict__ lb, uint16_t* __restrict__ xn)
{
    const int row = blockIdx.x;
    const int t = threadIdx.x;
    const float* xr = x + (size_t)row * 1024;
    const float4 xv = ((const float4*)xr)[t];
    float s  = xv.x + xv.y + xv.z + xv.w;
    float s2 = xv.x * xv.x + xv.y * xv.y + xv.z * xv.z + xv.w * xv.w;
#pragma unroll
    for (int off = 32; off > 0; off >>= 1) {
        s  += __shfl_xor(s, off);
        s2 += __shfl_xor(s2, off);
    }
    __shared__ float ps[4], ps2[4];
    const int w = t >> 6, lane = t & 63;
    if (lane == 0) { ps[w] = s; ps2[w] = s2; }
    __syncthreads();
    s  = ps[0] + ps[1] + ps[2] + ps[3];
    s2 = ps2[0] + ps2[1] + ps2[2] + ps2[3];
    const float mu  = s * (1.f / 1024.f);
    const float var = s2 * (1.f / 1024.f) - mu * mu;
    const float rs  = rsqrtf(var + 1e-5f);
    const float4 wv = ((const float4*)lw)[t];
    const float4 bv = ((const float4*)lb)[t];
    u16x4 o;
    o.x = f2bf((xv.x - mu) * rs * wv.x + bv.x);
    o.y = f2bf((xv.y - mu) * rs * wv.y + bv.y);
    o.z = f2bf((xv.z - mu) * rs * wv.z + bv.z);
    o.w = f2bf((xv.w - mu) * rs * wv.w + bv.w);
    ((u16x4*)(xn + (size_t)row * 1024))[t] = o;
}

// ---------------------------------------------------------------------------
// Transpose + cast weights: w[1024][1024] fp32 -> wt[1024][1024] bf16 (wt[h][d])
// ---------------------------------------------------------------------------
__global__ void k_wt(const float* __restrict__ wq, const float* __restrict__ wk,
                     const float* __restrict__ wv, uint16_t* __restrict__ wt)
{
    __shared__ float tile[32][33];
    const int z = blockIdx.z;
    const float* W = (z == 0) ? wq : ((z == 1) ? wk : wv);
    uint16_t* T = wt + (size_t)z * 1024 * 1024;
    const int c0 = blockIdx.x * 32, r0 = blockIdx.y * 32;
    const int tx = threadIdx.x, ty = threadIdx.y;  // (32,8)
#pragma unroll
    for (int i = 0; i < 4; i++)
        tile[ty + 8 * i][tx] = W[(size_t)(r0 + ty + 8 * i) * 1024 + c0 + tx];
    __syncthreads();
#pragma unroll
    for (int i = 0; i < 4; i++)
        T[(size_t)(c0 + ty + 8 * i) * 1024 + r0 + tx] = f2bf(tile[tx][ty + 8 * i]);
}

// Transpose v bf16 [2048][1024] -> vt [1024][2048] per batch
__global__ void k_vt(const uint16_t* __restrict__ v, uint16_t* __restrict__ vt)
{
    __shared__ uint16_t tile[32][33];
    const int b = blockIdx.z;
    const uint16_t* V = v + (size_t)b * 2048 * 1024;
    uint16_t* T = vt + (size_t)b * 2048 * 1024;
    const int c0 = blockIdx.x * 32, r0 = blockIdx.y * 32;
    const int tx = threadIdx.x, ty = threadIdx.y;  // (32,8)
#pragma unroll
    for (int i = 0; i < 4; i++)
        tile[ty + 8 * i][tx] = V[(size_t)(r0 + ty + 8 * i) * 1024 + c0 + tx];
    __syncthreads();
#pragma unroll
    for (int i = 0; i < 4; i++)
        T[(size_t)(c0 + ty + 8 * i) * 2048 + r0 + tx] = tile[tx][ty + 8 * i];
}

// ---------------------------------------------------------------------------
// Row softmax over S[8192][2048] fp32 (in place) + bf16 copy for the PV GEMM
// ---------------------------------------------------------------------------
__global__ __launch_bounds__(256) void k_softmax(
    float* __restrict__ S, uint16_t* __restrict__ attb)
{
    const size_t row = blockIdx.x;
    float* p = S + row * 2048;
    const int t = threadIdx.x;
    float4 a = ((float4*)p)[2 * t];
    float4 b = ((float4*)p)[2 * t + 1];
    float m = fmaxf(fmaxf(fmaxf(a.x, a.y), fmaxf(a.z, a.w)),
                    fmaxf(fmaxf(b.x, b.y), fmaxf(b.z, b.w)));
#pragma unroll
    for (int off = 32; off > 0; off >>= 1) m = fmaxf(m, __shfl_xor(m, off));
    __shared__ float pm[4], pl[4];
    const int w = t >> 6, lane = t & 63;
    if (lane == 0) pm[w] = m;
    __syncthreads();
    m = fmaxf(fmaxf(pm[0], pm[1]), fmaxf(pm[2], pm[3]));

    a.x = __expf(a.x - m); a.y = __expf(a.y - m);
    a.z = __expf(a.z - m); a.w = __expf(a.w - m);
    b.x = __expf(b.x - m); b.y = __expf(b.y - m);
    b.z = __expf(b.z - m); b.w = __expf(b.w - m);
    float s = a.x + a.y + a.z + a.w + b.x + b.y + b.z + b.w;
#pragma unroll
    for (int off = 32; off > 0; off >>= 1) s += __shfl_xor(s, off);
    if (lane == 0) pl[w] = s;
    __syncthreads();
    s = pl[0] + pl[1] + pl[2] + pl[3];
    const float inv = 1.f / s;

    a.x *= inv; a.y *= inv; a.z *= inv; a.w *= inv;
    b.x *= inv; b.y *= inv; b.z *= inv; b.w *= inv;
    ((float4*)p)[2 * t]     = a;
    ((float4*)p)[2 * t + 1] = b;

    uint16_t* q = attb + row * 2048 + t * 8;
    u16x4 o0, o1;
    o0.x = f2bf(a.x); o0.y = f2bf(a.y); o0.z = f2bf(a.z); o0.w = f2bf(a.w);
    o1.x = f2bf(b.x); o1.y = f2bf(b.y); o1.z = f2bf(b.z); o1.w = f2bf(b.w);
    ((u16x4*)q)[0] = o0;
    ((u16x4*)q)[1] = o1;
}

// ---------------------------------------------------------------------------
extern "C" void kernel_launch(void* const* d_in, const int* in_sizes, int n_in,
                              void* d_out, int out_size, void* d_ws, size_t ws_size,
                              hipStream_t stream)
{
    const float* x  = (const float*)d_in[0];
    const float* wq = (const float*)d_in[1];
    const float* bq = (const float*)d_in[2];
    const float* wk = (const float*)d_in[3];
    const float* bk = (const float*)d_in[4];
    const float* wv = (const float*)d_in[5];
    const float* bv = (const float*)d_in[6];
    const float* lw = (const float*)d_in[7];
    const float* lb = (const float*)d_in[8];

    float* att = (float*)d_out;                         // [4][2048][2048] = 64 MB
    float* out = (float*)d_out + (size_t)16777216;      // [4][2048][1024] = 32 MB

    // Scratch inside d_out's att region (dead until k_scores writes all of it):
    uint16_t* xn = (uint16_t*)d_out;                    // 8,388,608 elems (16.8 MB)
    uint16_t* wt = (uint16_t*)d_out + (size_t)8388608;  // 3,145,728 elems (6.3 MB)

    // ws layout (uint16 elems), exactly q+k+v = 25,165,824 elems = 50,331,648 B:
    //   [0, 8M)    q   -> dead after k_scores -> reused as vt
    //   [8M, 16M)  k   -> dead after k_scores ┐
    //   [16M, 24M) v   -> dead after k_vt     ┴-> reused as attb (16M elems)
    uint16_t* ws   = (uint16_t*)d_ws;
    uint16_t* q    = ws;
    uint16_t* k    = ws + (size_t)8388608;
    uint16_t* v    = ws + (size_t)2 * 8388608;
    uint16_t* vt   = ws;                                // overlays dead q
    uint16_t* attb = ws + (size_t)8388608;              // overlays dead k+v
    uint16_t* qkv  = q;

    if (ws_size < (size_t)50331648) return;  // OOB guard: fail clean, not crash

    k_ln<<<8192, 256, 0, stream>>>(x, lw, lb, xn);
    k_wt<<<dim3(32, 32, 3), dim3(32, 8), 0, stream>>>(wq, wk, wv, wt);
    k_qkv<<<dim3(8, 64, 3), 256, 0, stream>>>(xn, wt, bq, bk, bv, qkv);
    k_scores<<<dim3(16, 16, 4), 256, 0, stream>>>(q, k, att);   // frees q,k; kills xn/wt
    k_vt<<<dim3(32, 64, 4), dim3(32, 8), 0, stream>>>(v, vt);   // vt over dead q
    k_softmax<<<8192, 256, 0, stream>>>(att, attb);             // attb over dead k+v
    k_out<<<dim3(8, 16, 4), 256, 0, stream>>>(attb, vt, out);
}

// Round 4
// 338.044 us; speedup vs baseline: 1.0582x; 1.0582x over previous
//
#include <hip/hip_runtime.h>
#include <stdint.h>

// ---------------------------------------------------------------------------
// SelfAttention: LN -> QKV (bf16 MFMA GEMM) -> S=QK^T/32 -> softmax -> att*V
// B=4, N=2048, D=H=1024. Outputs: att fp32 [4,2048,2048] ++ out fp32 [4,2048,1024]
// R4: GEMM K-loop BK=64 (half the barriers) + XOR-swizzled LDS segs (kills the
//     8-way ds_read_b128 bank conflicts seen in R3: SQ_LDS_BANK_CONFLICT=6.3M).
// Scratch: d_out att region hosts xn+wt until k_scores; ws = q|k|v (50.3 MB),
//          vt overlays dead q, attb overlays dead k+v.
// ---------------------------------------------------------------------------

typedef __attribute__((ext_vector_type(8))) short short8;   // 8 bf16 (4 VGPRs)
typedef __attribute__((ext_vector_type(4))) float floatx4;  // MFMA acc
typedef __attribute__((ext_vector_type(4))) uint16_t u16x4;

__device__ __forceinline__ uint16_t f2bf(float f) {
    union { float f; uint32_t u; } v; v.f = f;
    uint32_t r = v.u + 0x7fffu + ((v.u >> 16) & 1u);  // RNE
    return (uint16_t)(r >> 16);
}

// async global->LDS, 16B per lane. LDS dest is wave-uniform base + lane*16.
typedef const uint32_t __attribute__((address_space(1)))* gas1_t;
typedef uint32_t __attribute__((address_space(3)))* las3_t;
__device__ __forceinline__ void gload_lds16(const uint16_t* g, uint16_t* l) {
    __builtin_amdgcn_global_load_lds((gas1_t)g, (las3_t)l, 16, 0, 0);
}

// ---------------------------------------------------------------------------
// C = A * Bt^T. A:[M,K] bf16 row-major, Bt:[N,K] bf16 row-major.
// Block tile 128x128, BK=64, 256 threads (4 waves, 2x2 of 64x64 per wave).
// LDS tiles [128][64] with 16B-seg XOR swizzle: phys_seg = seg ^ (row & 7).
//   - staging thread t fetches global seg (t&7)^(row&7) into phys slot (t&7)
//   - readers fetch phys_seg = (ks*4+quad) ^ (lrow&7)  -> 2 lanes/bank, free
// EPI: 0 = fp32 store * alpha;  1 = bf16 store + bias;  2 = fp32 store.
// ---------------------------------------------------------------------------
#define BM 128
#define BN 128
#define BK2 64

template<int EPI>
__device__ __forceinline__ void gemm_bt_body(
    const uint16_t* __restrict__ A, const uint16_t* __restrict__ Bt, int K,
    float* __restrict__ Cf, uint16_t* __restrict__ Cb, int ldc,
    const float* __restrict__ bias, float alpha)
{
    __shared__ uint16_t lA[BM * BK2];  // 16 KB
    __shared__ uint16_t lB[BN * BK2];  // 16 KB

    const int t  = threadIdx.x;
    const int m0 = blockIdx.y * BM;
    const int n0 = blockIdx.x * BN;

    // staging: thread t covers row srow(+32*r), fetches swizzled seg sseg
    const int srow = t >> 3;                  // 0..31
    const int sseg = (t & 7) ^ (srow & 7);    // global 16B-seg this thread fetches
    const uint16_t* ga = A + (size_t)(m0 + srow) * K + sseg * 8;
    const uint16_t* gb = Bt + (size_t)(n0 + srow) * K + sseg * 8;
    uint16_t* la = &lA[t * 8];                // phys slot (row srow, seg t&7)
    uint16_t* lb = &lB[t * 8];
    const size_t rstep = (size_t)32 * K;      // +32 rows (swizzle invariant mod 8)

    const int lane = t & 63;
    const int w    = t >> 6;
    const int quad = lane >> 4;
    const int lrow = lane & 15;
    const int wm   = (w & 1) * 64;
    const int wn   = (w >> 1) * 64;
    const int swz  = lrow & 7;

    floatx4 acc[4][4];
#pragma unroll
    for (int i = 0; i < 4; i++)
#pragma unroll
        for (int j = 0; j < 4; j++)
            acc[i][j] = floatx4{0.f, 0.f, 0.f, 0.f};

    for (int k0 = 0; k0 < K; k0 += BK2) {
        __syncthreads();  // LDS reuse guard
        gload_lds16(ga + k0,             la);
        gload_lds16(ga + rstep + k0,     la + 2048);
        gload_lds16(ga + 2 * rstep + k0, la + 4096);
        gload_lds16(ga + 3 * rstep + k0, la + 6144);
        gload_lds16(gb + k0,             lb);
        gload_lds16(gb + rstep + k0,     lb + 2048);
        gload_lds16(gb + 2 * rstep + k0, lb + 4096);
        gload_lds16(gb + 3 * rstep + k0, lb + 6144);
        __syncthreads();  // drains vmcnt (global_load_lds)

#pragma unroll
        for (int ks = 0; ks < 2; ks++) {
            short8 af[4], bf[4];
#pragma unroll
            for (int mi = 0; mi < 4; mi++)
                af[mi] = *(const short8*)&lA[(wm + mi * 16 + lrow) * BK2 +
                                             (((ks * 4 + quad) ^ swz) * 8)];
#pragma unroll
            for (int ni = 0; ni < 4; ni++)
                bf[ni] = *(const short8*)&lB[(wn + ni * 16 + lrow) * BK2 +
                                             (((ks * 4 + quad) ^ swz) * 8)];
#pragma unroll
            for (int mi = 0; mi < 4; mi++)
#pragma unroll
                for (int ni = 0; ni < 4; ni++)
                    acc[mi][ni] = __builtin_amdgcn_mfma_f32_16x16x32_bf16(
                        af[mi], bf[ni], acc[mi][ni], 0, 0, 0);
        }
    }

    // epilogue: C/D layout col=lane&15, row=quad*4+reg  [verified m89/m91]
#pragma unroll
    for (int mi = 0; mi < 4; mi++) {
#pragma unroll
        for (int ni = 0; ni < 4; ni++) {
            const int row = m0 + wm + mi * 16 + quad * 4;
            const int col = n0 + wn + ni * 16 + lrow;
#pragma unroll
            for (int r = 0; r < 4; r++) {
                const float v = acc[mi][ni][r];
                if (EPI == 0) {
                    Cf[(size_t)(row + r) * ldc + col] = v * alpha;
                } else if (EPI == 1) {
                    Cb[(size_t)(row + r) * ldc + col] = f2bf(v + bias[col]);
                } else {
                    Cf[(size_t)(row + r) * ldc + col] = v;
                }
            }
        }
    }
}

// q/k/v = xn @ w{q,k,v} + b   (z selects weight); writes bf16 row-major
__global__ __launch_bounds__(256) void k_qkv(
    const uint16_t* __restrict__ xn, const uint16_t* __restrict__ wt,
    const float* __restrict__ bq, const float* __restrict__ bk,
    const float* __restrict__ bv, uint16_t* __restrict__ qkv)
{
    const int z = blockIdx.z;
    const uint16_t* Bt = wt + (size_t)z * 1024 * 1024;
    const float* bias = (z == 0) ? bq : ((z == 1) ? bk : bv);
    uint16_t* C = qkv + (size_t)z * 8192 * 1024;
    gemm_bt_body<1>(xn, Bt, 1024, nullptr, C, 1024, bias, 0.f);
}

// S = q @ k^T * (1/32), fp32 into d_out att region
__global__ __launch_bounds__(256) void k_scores(
    const uint16_t* __restrict__ q, const uint16_t* __restrict__ k,
    float* __restrict__ S)
{
    const int z = blockIdx.z;
    gemm_bt_body<0>(q + (size_t)z * 2048 * 1024, k + (size_t)z * 2048 * 1024, 1024,
                    S + (size_t)z * 2048 * 2048, nullptr, 2048, nullptr, 0.03125f);
}

// out = att_bf16 @ vt^T, fp32
__global__ __launch_bounds__(256) void k_out(
    const uint16_t* __restrict__ attb, const uint16_t* __restrict__ vt,
    float* __restrict__ out)
{
    const int z = blockIdx.z;
    gemm_bt_body<2>(attb + (size_t)z * 2048 * 2048, vt + (size_t)z * 1024 * 2048, 2048,
                    out + (size_t)z * 2048 * 1024, nullptr, 1024, nullptr, 0.f);
}

// ---------------------------------------------------------------------------
// LayerNorm rows of x[8192][1024] -> bf16 xn
// ---------------------------------------------------------------------------
__global__ __launch_bounds__(256) void k_ln(
    const float* __restrict__ x, const float* __restrict__ lw,
    const float* __restrict__ lb, uint16_t* __restrict__ xn)
{
    const int row = blockIdx.x;
    const int t = threadIdx.x;
    const float* xr = x + (size_t)row * 1024;
    const float4 xv = ((const float4*)xr)[t];
    float s  = xv.x + xv.y + xv.z + xv.w;
    float s2 = xv.x * xv.x + xv.y * xv.y + xv.z * xv.z + xv.w * xv.w;
#pragma unroll
    for (int off = 32; off > 0; off >>= 1) {
        s  += __shfl_xor(s, off);
        s2 += __shfl_xor(s2, off);
    }
    __shared__ float ps[4], ps2[4];
    const int w = t >> 6, lane = t & 63;
    if (lane == 0) { ps[w] = s; ps2[w] = s2; }
    __syncthreads();
    s  = ps[0] + ps[1] + ps[2] + ps[3];
    s2 = ps2[0] + ps2[1] + ps2[2] + ps2[3];
    const float mu  = s * (1.f / 1024.f);
    const float var = s2 * (1.f / 1024.f) - mu * mu;
    const float rs  = rsqrtf(var + 1e-5f);
    const float4 wv = ((const float4*)lw)[t];
    const float4 bv = ((const float4*)lb)[t];
    u16x4 o;
    o.x = f2bf((xv.x - mu) * rs * wv.x + bv.x);
    o.y = f2bf((xv.y - mu) * rs * wv.y + bv.y);
    o.z = f2bf((xv.z - mu) * rs * wv.z + bv.z);
    o.w = f2bf((xv.w - mu) * rs * wv.w + bv.w);
    ((u16x4*)(xn + (size_t)row * 1024))[t] = o;
}

// ---------------------------------------------------------------------------
// Transpose + cast weights: w[1024][1024] fp32 -> wt[1024][1024] bf16 (wt[h][d])
// ---------------------------------------------------------------------------
__global__ void k_wt(const float* __restrict__ wq, const float* __restrict__ wk,
                     const float* __restrict__ wv, uint16_t* __restrict__ wt)
{
    __shared__ float tile[32][33];
    const int z = blockIdx.z;
    const float* W = (z == 0) ? wq : ((z == 1) ? wk : wv);
    uint16_t* T = wt + (size_t)z * 1024 * 1024;
    const int c0 = blockIdx.x * 32, r0 = blockIdx.y * 32;
    const int tx = threadIdx.x, ty = threadIdx.y;  // (32,8)
#pragma unroll
    for (int i = 0; i < 4; i++)
        tile[ty + 8 * i][tx] = W[(size_t)(r0 + ty + 8 * i) * 1024 + c0 + tx];
    __syncthreads();
#pragma unroll
    for (int i = 0; i < 4; i++)
        T[(size_t)(c0 + ty + 8 * i) * 1024 + r0 + tx] = f2bf(tile[tx][ty + 8 * i]);
}

// ---------------------------------------------------------------------------
// Transpose v bf16 [2048][1024] -> vt [1024][2048] per batch. 64x64 tiles,
// u16x4 loads and stores (R3's version did scattered 2-byte stores).
// ---------------------------------------------------------------------------
__global__ __launch_bounds__(256) void k_vt(
    const uint16_t* __restrict__ v, uint16_t* __restrict__ vt)
{
    __shared__ uint16_t tile[64][68];  // +4 pad keeps 8B align, breaks conflicts
    const int b = blockIdx.z;
    const uint16_t* V = v + (size_t)b * 2048 * 1024;
    uint16_t* T = vt + (size_t)b * 1024 * 2048;
    const int h0 = blockIdx.x * 64, t0 = blockIdx.y * 64;
    const int t = threadIdx.x;
    const int rr = t >> 4;          // 0..15
    const int cc = (t & 15) * 4;    // 0..60
#pragma unroll
    for (int i = 0; i < 4; i++) {
        const int tok = rr + 16 * i;
        *(u16x4*)&tile[tok][cc] =
            *(const u16x4*)&V[(size_t)(t0 + tok) * 1024 + h0 + cc];
    }
    __syncthreads();
#pragma unroll
    for (int i = 0; i < 4; i++) {
        const int h = rr + 16 * i;
        u16x4 o;
        o.x = tile[cc + 0][h];
        o.y = tile[cc + 1][h];
        o.z = tile[cc + 2][h];
        o.w = tile[cc + 3][h];
        *(u16x4*)&T[(size_t)(h0 + h) * 2048 + t0 + cc] = o;
    }
}

// ---------------------------------------------------------------------------
// Row softmax over S[8192][2048] fp32 (in place) + bf16 copy for the PV GEMM
// ---------------------------------------------------------------------------
__global__ __launch_bounds__(256) void k_softmax(
    float* __restrict__ S, uint16_t* __restrict__ attb)
{
    const size_t row = blockIdx.x;
    float* p = S + row * 2048;
    const int t = threadIdx.x;
    float4 a = ((float4*)p)[2 * t];
    float4 b = ((float4*)p)[2 * t + 1];
    float m = fmaxf(fmaxf(fmaxf(a.x, a.y), fmaxf(a.z, a.w)),
                    fmaxf(fmaxf(b.x, b.y), fmaxf(b.z, b.w)));
#pragma unroll
    for (int off = 32; off > 0; off >>= 1) m = fmaxf(m, __shfl_xor(m, off));
    __shared__ float pm[4], pl[4];
    const int w = t >> 6, lane = t & 63;
    if (lane == 0) pm[w] = m;
    __syncthreads();
    m = fmaxf(fmaxf(pm[0], pm[1]), fmaxf(pm[2], pm[3]));

    a.x = __expf(a.x - m); a.y = __expf(a.y - m);
    a.z = __expf(a.z - m); a.w = __expf(a.w - m);
    b.x = __expf(b.x - m); b.y = __expf(b.y - m);
    b.z = __expf(b.z - m); b.w = __expf(b.w - m);
    float s = a.x + a.y + a.z + a.w + b.x + b.y + b.z + b.w;
#pragma unroll
    for (int off = 32; off > 0; off >>= 1) s += __shfl_xor(s, off);
    if (lane == 0) pl[w] = s;
    __syncthreads();
    s = pl[0] + pl[1] + pl[2] + pl[3];
    const float inv = 1.f / s;

    a.x *= inv; a.y *= inv; a.z *= inv; a.w *= inv;
    b.x *= inv; b.y *= inv; b.z *= inv; b.w *= inv;
    ((float4*)p)[2 * t]     = a;
    ((float4*)p)[2 * t + 1] = b;

    uint16_t* q = attb + row * 2048 + t * 8;
    u16x4 o0, o1;
    o0.x = f2bf(a.x); o0.y = f2bf(a.y); o0.z = f2bf(a.z); o0.w = f2bf(a.w);
    o1.x = f2bf(b.x); o1.y = f2bf(b.y); o1.z = f2bf(b.z); o1.w = f2bf(b.w);
    ((u16x4*)q)[0] = o0;
    ((u16x4*)q)[1] = o1;
}

// ---------------------------------------------------------------------------
extern "C" void kernel_launch(void* const* d_in, const int* in_sizes, int n_in,
                              void* d_out, int out_size, void* d_ws, size_t ws_size,
                              hipStream_t stream)
{
    const float* x  = (const float*)d_in[0];
    const float* wq = (const float*)d_in[1];
    const float* bq = (const float*)d_in[2];
    const float* wk = (const float*)d_in[3];
    const float* bk = (const float*)d_in[4];
    const float* wv = (const float*)d_in[5];
    const float* bv = (const float*)d_in[6];
    const float* lw = (const float*)d_in[7];
    const float* lb = (const float*)d_in[8];

    float* att = (float*)d_out;                         // [4][2048][2048] = 64 MB
    float* out = (float*)d_out + (size_t)16777216;      // [4][2048][1024] = 32 MB

    // Scratch inside d_out's att region (dead until k_scores writes all of it):
    uint16_t* xn = (uint16_t*)d_out;                    // 8,388,608 elems (16.8 MB)
    uint16_t* wt = (uint16_t*)d_out + (size_t)8388608;  // 3,145,728 elems (6.3 MB)

    // ws layout (uint16 elems), exactly q+k+v = 25,165,824 elems = 50,331,648 B:
    //   [0, 8M)    q   -> dead after k_scores -> reused as vt
    //   [8M, 16M)  k   -> dead after k_scores ┐
    //   [16M, 24M) v   -> dead after k_vt     ┴-> reused as attb (16M elems)
    uint16_t* ws   = (uint16_t*)d_ws;
    uint16_t* q    = ws;
    uint16_t* k    = ws + (size_t)8388608;
    uint16_t* v    = ws + (size_t)2 * 8388608;
    uint16_t* vt   = ws;                                // overlays dead q
    uint16_t* attb = ws + (size_t)8388608;              // overlays dead k+v
    uint16_t* qkv  = q;

    if (ws_size < (size_t)50331648) return;  // OOB guard: fail clean, not crash

    k_ln<<<8192, 256, 0, stream>>>(x, lw, lb, xn);
    k_wt<<<dim3(32, 32, 3), dim3(32, 8), 0, stream>>>(wq, wk, wv, wt);
    k_qkv<<<dim3(8, 64, 3), 256, 0, stream>>>(xn, wt, bq, bk, bv, qkv);
    k_scores<<<dim3(16, 16, 4), 256, 0, stream>>>(q, k, att);   // frees q,k
    k_vt<<<dim3(16, 32, 4), 256, 0, stream>>>(v, vt);           // vt over dead q
    k_softmax<<<8192, 256, 0, stream>>>(att, attb);             // attb over dead k+v
    k_out<<<dim3(8, 16, 4), 256, 0, stream>>>(attb, vt, out);
}